// Round 8
// baseline (509.180 us; speedup 1.0000x reference)
//
#include <hip/hip_runtime.h>

// Problem constants (from reference)
constexpr int N   = 50000;
constexpr int E   = 800000;
constexpr int FIN = 512;
constexpr int H1v = 256;
constexpr int H2v = 32;
constexpr int Cv  = 16;

constexpr int NBLK = (N + 1023) / 1024;  // 49 scan blocks

typedef __attribute__((ext_vector_type(8))) short short8;            // 8 bf16 (MFMA frag)
typedef __attribute__((ext_vector_type(4))) float f32x4;             // MFMA C/D frag
typedef __attribute__((ext_vector_type(4))) unsigned short us4;      // 4 bf16
typedef __attribute__((ext_vector_type(8))) unsigned short us8;      // 8 bf16 (16 B)
typedef __attribute__((ext_vector_type(4))) unsigned int uint4v;

// fp32 -> bf16 round-to-nearest-even, and back
__device__ inline unsigned short f2bf(float f) {
    unsigned u = __float_as_uint(f);
    return (unsigned short)((u + 0x7FFFu + ((u >> 16) & 1u)) >> 16);
}
__device__ inline float bf2f(unsigned short b) { return __uint_as_float(((unsigned)b) << 16); }

// ---------------- init: cnt zeroing + W1 split, fused (independent data) --------

__global__ __launch_bounds__(256) void k_init(const float* __restrict__ W,
                                              unsigned short* __restrict__ Wf,
                                              int* __restrict__ cnt) {
    const int b = blockIdx.x;
    if (b < 64) {
        int t = b * 256 + threadIdx.x;  // 0..16383
        int l = t & 63, nt = (t >> 6) & 15, kt = t >> 10;
        int n = nt * 16 + (l & 15);
        int kb = kt * 32 + (l >> 4) * 8;
        short8 h8, l8;
#pragma unroll
        for (int j = 0; j < 8; ++j) {
            float w = W[(size_t)(kb + j) * H1v + n];
            unsigned short h = f2bf(w);
            h8[j] = (short)h;
            l8[j] = (short)f2bf(w - bf2f(h));
        }
        size_t base = ((size_t)(kt * 16 + nt) * 2) * 512 + (size_t)l * 8;
        *(short8*)(Wf + base) = h8;
        *(short8*)(Wf + base + 512) = l8;
    } else {
        int i = (b - 64) * 256 + threadIdx.x;
        if (i <= N) cnt[i] = 0;
    }
}

// ---------------- degree histogram / CSR build ----------------

__global__ __launch_bounds__(256) void k_hist(const int* __restrict__ dst,
                                              int* __restrict__ cnt) {
    int e = blockIdx.x * 256 + threadIdx.x;
    if (e < E) atomicAdd(&cnt[dst[e]], 1);
}

// Phase 1: per-block (1024 elems) sums.
__global__ __launch_bounds__(256) void k_scan_part(const int* __restrict__ cnt,
                                                   int* __restrict__ bsum) {
    __shared__ int red[256];
    const int t = threadIdx.x;
    const int base = blockIdx.x * 1024 + t * 4;
    int s = 0;
#pragma unroll
    for (int i = 0; i < 4; ++i) {
        int idx = base + i;
        if (idx < N) s += cnt[idx];
    }
    red[t] = s;
    __syncthreads();
    for (int off = 128; off > 0; off >>= 1) {
        if (t < off) red[t] += red[t + off];
        __syncthreads();
    }
    if (t == 0) bsum[blockIdx.x] = red[0];
}

// Phase 2 (fused top + final)
__global__ __launch_bounds__(256) void k_scan_final(const int* __restrict__ cnt,
                                                    const int* __restrict__ bsum,
                                                    int* __restrict__ row_ptr,
                                                    int* __restrict__ cursor,
                                                    float* __restrict__ dinv) {
    __shared__ int sums[256];
    __shared__ int s_bofs, s_tot;
    const int t = threadIdx.x;

    if (t < 64) {
        int v = (t < NBLK) ? bsum[t] : 0;
        int pre = (t < (int)blockIdx.x) ? v : 0;
#pragma unroll
        for (int off = 32; off > 0; off >>= 1) {
            pre += __shfl_down(pre, off, 64);
            v   += __shfl_down(v, off, 64);
        }
        if (t == 0) { s_bofs = pre; s_tot = v; }
    }

    const int base = blockIdx.x * 1024 + t * 4;
    int v[4];
    int local = 0;
#pragma unroll
    for (int i = 0; i < 4; ++i) {
        int idx = base + i;
        v[i] = (idx < N) ? cnt[idx] : 0;
        local += v[i];
    }
    sums[t] = local;
    __syncthreads();
    for (int off = 1; off < 256; off <<= 1) {
        int u = (t >= off) ? sums[t - off] : 0;
        __syncthreads();
        sums[t] += u;
        __syncthreads();
    }
    int run = s_bofs + sums[t] - local;  // exclusive thread offset
#pragma unroll
    for (int i = 0; i < 4; ++i) {
        int idx = base + i;
        if (idx < N) {
            row_ptr[idx] = run;
            cursor[idx] = run;
            dinv[idx] = rsqrtf(1.0f + (float)v[i]);  // +1 self-loop
        }
        run += v[i];
    }
    if (blockIdx.x == NBLK - 1 && t == 0) row_ptr[N] = s_tot;  // == E
}

__global__ __launch_bounds__(256) void k_permute(const int* __restrict__ src,
                                                 const int* __restrict__ dst,
                                                 int* __restrict__ cursor,
                                                 int* __restrict__ srcs) {
    int e = blockIdx.x * 256 + threadIdx.x;
    if (e < E) {
        int pos = atomicAdd(&cursor[dst[e]], 1);
        srcs[pos] = src[e];
    }
}

// ---------------- GEMM 1 (MFMA, split-bf16 x3): [N,512]@[512,256] ---------------
// ROUND 16: structure frozen at R14 best (BK=64, conflict-free, ~77us). Split
// into 4 row-chunk DISPATCHES (~20us each) as a DIAGNOSTIC: drops gemm1 out of
// the rocprof top-5 window so the true biggest remaining kernels (~348us total,
// never yet profiled) surface with counters next round. Cost: few us of launch
// overhead. (Ledger: A-staging null, issue-order null, barrier-halving null,
// B-LDS -18%, lb(256,8) spill, occupancy 2->4 = only win.)

__device__ inline void split_pair(float x0, float x1, unsigned& hp, unsigned& lp) {
    unsigned u0 = __float_as_uint(x0), u1 = __float_as_uint(x1);
    unsigned h0 = u0 & 0xffff0000u, h1 = u1 & 0xffff0000u;
    float l0 = x0 - __uint_as_float(h0);
    float l1 = x1 - __uint_as_float(h1);
    hp = __builtin_amdgcn_perm(u1, u0, 0x07060302u);  // [u0.hi16, u1.hi16]
    lp = __builtin_amdgcn_perm(__float_as_uint(l1), __float_as_uint(l0), 0x07060302u);
}

__device__ inline void split_frag(const float4& a, const float4& b, short8& hi, short8& lo) {
    unsigned h0, h1, h2, h3, l0, l1, l2, l3;
    split_pair(a.x, a.y, h0, l0);
    split_pair(a.z, a.w, h1, l1);
    split_pair(b.x, b.y, h2, l2);
    split_pair(b.z, b.w, h3, l3);
    uint4v h, l;
    h[0] = h0; h[1] = h1; h[2] = h2; h[3] = h3;
    l[0] = l0; l[1] = l1; l[2] = l2; l[3] = l3;
    hi = __builtin_bit_cast(short8, h);
    lo = __builtin_bit_cast(short8, l);
}

// Stage one 64-row x 64-col fp32 X tile into LDS (16 KB), XOR-swizzled.
__device__ inline void stage_x_tile(const float* __restrict__ X, int brow, int k0,
                                    float* lds, int tid) {
    const int wbase = tid & ~63;  // wave-uniform chunk base
#pragma unroll
    for (int c = 0; c < 4; ++c) {
        int q = c * 256 + tid;
        int row = q >> 4;
        int gc = ((q & 15) ^ (row & 15)) << 2;  // swizzled source col (floats)
        int r = brow + row;
        const float* src = X + (size_t)(r < N ? r : 0) * FIN + k0 + gc;
        float* dst = lds + (size_t)(c * 256 + wbase) * 4;  // wave-uniform, lane adds 16B
        __builtin_amdgcn_global_load_lds((const __attribute__((address_space(1))) void*)src,
                                         (__attribute__((address_space(3))) void*)dst,
                                         16, 0, 0);
    }
}

__global__ __launch_bounds__(256, 4) void k_gemm1_mfma(const float* __restrict__ X,
                                                       const unsigned short* __restrict__ Wf,
                                                       const float* __restrict__ dinv,
                                                       unsigned short* __restrict__ Hout,
                                                       int browBase) {
    __shared__ float As[2][4096];  // 2 x (64 rows x 64 cols) fp32 = 32 KB
    const int tid = threadIdx.x;
    const int w = tid >> 6, l = tid & 63;
    const int wr = w >> 1, wc = w & 1;        // wave: 32-row group x 64-col group
    const int brow = browBase + blockIdx.x * 64;  // block row base
    const int row0 = brow + wr * 32;          // this wave's global row base
    const int wrow = wr * 32;                 // this wave's LDS-local row base
    const int colb = blockIdx.y;
    const int lm = l & 15;
    const int lk2 = (l >> 4) * 2;             // fragment granule pair base (16B units)

    // B frag lane pointer (tiles ntg = colb*8 + wc*4 + j)
    const unsigned short* bp0 = Wf + (size_t)(colb * 8 + wc * 4) * 1024 + (size_t)l * 8;

    f32x4 acc[2][4];
#pragma unroll
    for (int i = 0; i < 2; ++i)
#pragma unroll
        for (int j = 0; j < 4; ++j) acc[i][j] = (f32x4)0.f;

    // prologue: stage K-tile 0 (64 cols)
    stage_x_tile(X, brow, 0, As[0], tid);

    for (int kt = 0; kt < 8; ++kt) {
        const int cur = kt & 1;
        __syncthreads();  // drains vmcnt(0): As[cur] staged & visible

        // B frags for sub-step 0 (ktg = 2*kt), L2-hot frag layout
        const unsigned short* bpA = bp0 + (size_t)(2 * kt) * 16384;
        short8 B0h[4], B0l[4];
#pragma unroll
        for (int j = 0; j < 4; ++j) {
            B0h[j] = *(const short8*)(bpA + j * 1024);
            B0l[j] = *(const short8*)(bpA + j * 1024 + 512);
        }

        // stage next 64-col K-tile (completes during the two MFMA phases)
        if (kt < 7) stage_x_tile(X, brow, (kt + 1) * 64, As[cur ^ 1], tid);

        const float* Ab = As[cur];

        // ---- sub-step 0: granules [0,8) ----
        short8 Ah[2], Al[2];
#pragma unroll
        for (int i = 0; i < 2; ++i) {
            int row = wrow + i * 16 + lm;
            const float* rbp = Ab + row * 64;
            int p = row & 15;
            float4 a0 = *(const float4*)(rbp + ((lk2 ^ p) << 2));
            float4 a1 = *(const float4*)(rbp + (((lk2 + 1) ^ p) << 2));
            split_frag(a0, a1, Ah[i], Al[i]);
        }

        // B frags for sub-step 1 issued BEFORE MFMA block 0 (latency covered by it)
        const unsigned short* bpB = bpA + 16384;
        short8 B1h[4], B1l[4];
#pragma unroll
        for (int j = 0; j < 4; ++j) {
            B1h[j] = *(const short8*)(bpB + j * 1024);
            B1l[j] = *(const short8*)(bpB + j * 1024 + 512);
        }

#pragma unroll
        for (int i = 0; i < 2; ++i)
#pragma unroll
            for (int j = 0; j < 4; ++j) {
                acc[i][j] = __builtin_amdgcn_mfma_f32_16x16x32_bf16(Ah[i], B0h[j], acc[i][j], 0, 0, 0);
                acc[i][j] = __builtin_amdgcn_mfma_f32_16x16x32_bf16(Ah[i], B0l[j], acc[i][j], 0, 0, 0);
                acc[i][j] = __builtin_amdgcn_mfma_f32_16x16x32_bf16(Al[i], B0h[j], acc[i][j], 0, 0, 0);
            }

        // ---- sub-step 1: granules [8,16) ----
#pragma unroll
        for (int i = 0; i < 2; ++i) {
            int row = wrow + i * 16 + lm;
            const float* rbp = Ab + row * 64;
            int p = row & 15;
            int g0 = lk2 + 8;
            float4 a0 = *(const float4*)(rbp + ((g0 ^ p) << 2));
            float4 a1 = *(const float4*)(rbp + (((g0 + 1) ^ p) << 2));
            split_frag(a0, a1, Ah[i], Al[i]);
        }

#pragma unroll
        for (int i = 0; i < 2; ++i)
#pragma unroll
            for (int j = 0; j < 4; ++j) {
                acc[i][j] = __builtin_amdgcn_mfma_f32_16x16x32_bf16(Ah[i], B1h[j], acc[i][j], 0, 0, 0);
                acc[i][j] = __builtin_amdgcn_mfma_f32_16x16x32_bf16(Ah[i], B1l[j], acc[i][j], 0, 0, 0);
                acc[i][j] = __builtin_amdgcn_mfma_f32_16x16x32_bf16(Al[i], B1h[j], acc[i][j], 0, 0, 0);
            }
    }

    // ---- epilogue: C row = (l>>4)*4 + reg, col = l&15 ; *dinv[row], store bf16 ----
    const int col0 = colb * 128 + wc * 64;
#pragma unroll
    for (int i = 0; i < 2; ++i) {
        int rbase = row0 + i * 16 + (l >> 4) * 4;
        float dv[4];
        bool okr[4];
#pragma unroll
        for (int r = 0; r < 4; ++r) {
            int rr = rbase + r;
            okr[r] = rr < N;
            dv[r] = okr[r] ? dinv[rr] : 0.f;
        }
#pragma unroll
        for (int j = 0; j < 4; ++j) {
            int col = col0 + j * 16 + lm;
#pragma unroll
            for (int r = 0; r < 4; ++r)
                if (okr[r]) Hout[(size_t)(rbase + r) * H1v + col] = f2bf(acc[i][j][r] * dv[r]);
        }
    }
}

// ---------------- GEMM 2: [N,256] @ [256,32] fp32 in, *dinv, bf16 out ----------------
// ROUND 16: 32 rows/block (was 8): W2 LDS-staging traffic 200MB -> 50MB, 4
// outputs/thread (rows r0 + (t>>5) + 8i), 4x per-thread ILP. Bit-identical.

__global__ __launch_bounds__(256) void k_gemm2(const float* __restrict__ A,
                                               const float* __restrict__ W,
                                               const float* __restrict__ dinv,
                                               unsigned short* __restrict__ Hout) {
    __shared__ float Ws[H1v * H2v];  // 32 KB
    const int tid = threadIdx.x;
#pragma unroll
    for (int i = 0; i < 8; ++i) {
        int off = tid * 4 + i * 1024;
        *(float4*)(&Ws[off]) = *(const float4*)(W + off);
    }
    __syncthreads();

    const int r0 = blockIdx.x * 32 + (tid >> 5);
    const int col = tid & 31;
    const float* arow = A + (size_t)r0 * H1v;
    bool ok[4];
    float sum[4];
#pragma unroll
    for (int i = 0; i < 4; ++i) { ok[i] = (r0 + 8 * i) < N; sum[i] = 0.f; }
#pragma unroll 2
    for (int k = 0; k < H1v; k += 4) {
        float4 a4[4];
#pragma unroll
        for (int i = 0; i < 4; ++i)
            a4[i] = ok[i] ? *(const float4*)(arow + (size_t)(8 * i) * H1v + k)
                          : make_float4(0.f, 0.f, 0.f, 0.f);
        float w0 = Ws[(k + 0) * H2v + col];
        float w1 = Ws[(k + 1) * H2v + col];
        float w2 = Ws[(k + 2) * H2v + col];
        float w3 = Ws[(k + 3) * H2v + col];
#pragma unroll
        for (int i = 0; i < 4; ++i) {
            sum[i] = fmaf(a4[i].x, w0, sum[i]);
            sum[i] = fmaf(a4[i].y, w1, sum[i]);
            sum[i] = fmaf(a4[i].z, w2, sum[i]);
            sum[i] = fmaf(a4[i].w, w3, sum[i]);
        }
    }
#pragma unroll
    for (int i = 0; i < 4; ++i) {
        int r = r0 + 8 * i;
        if (ok[i]) Hout[(size_t)r * H2v + col] = f2bf(sum[i] * dinv[r]);
    }
}

// ---------------- CSR aggregation D=256 (atomic-free, bf16 msgs, fp32 accum) -----
// ROUND 16: unroll 8 (deg avg 16 -> full row in ~2 batches of 8 outstanding 16B
// gathers). Summation regroup proven absmax-neutral (R5->R6 identical absmax).

__global__ __launch_bounds__(256) void k_agg_d256(const unsigned short* __restrict__ h,
                                                  const int* __restrict__ rp,
                                                  const int* __restrict__ srcs,
                                                  const float* __restrict__ dinv,
                                                  const float* __restrict__ bias,
                                                  float* __restrict__ out) {
    const int half = threadIdx.x >> 5;     // row slot 0..7 in block
    const int lane = threadIdx.x & 31;
    const int d = blockIdx.x * 8 + half;
    if (d >= N) return;
    const int beg = rp[d], end = rp[d + 1];
    const int fo = lane * 8;               // 8 bf16 = 16 B per lane
    const unsigned short* hb = h + fo;
    us8 sv = *(const us8*)(hb + (size_t)d * H1v);  // self-loop
    float a[8];
#pragma unroll
    for (int q = 0; q < 8; ++q) a[q] = bf2f(sv[q]);
    int j = beg;
    for (; j + 7 < end; j += 8) {  // 8 independent 16B gathers per row
        us8 v0 = *(const us8*)(hb + (size_t)srcs[j] * H1v);
        us8 v1 = *(const us8*)(hb + (size_t)srcs[j + 1] * H1v);
        us8 v2 = *(const us8*)(hb + (size_t)srcs[j + 2] * H1v);
        us8 v3 = *(const us8*)(hb + (size_t)srcs[j + 3] * H1v);
        us8 v4 = *(const us8*)(hb + (size_t)srcs[j + 4] * H1v);
        us8 v5 = *(const us8*)(hb + (size_t)srcs[j + 5] * H1v);
        us8 v6 = *(const us8*)(hb + (size_t)srcs[j + 6] * H1v);
        us8 v7 = *(const us8*)(hb + (size_t)srcs[j + 7] * H1v);
#pragma unroll
        for (int q = 0; q < 8; ++q)
            a[q] += ((bf2f(v0[q]) + bf2f(v1[q])) + (bf2f(v2[q]) + bf2f(v3[q])))
                  + ((bf2f(v4[q]) + bf2f(v5[q])) + (bf2f(v6[q]) + bf2f(v7[q])));
    }
    for (; j + 3 < end; j += 4) {
        us8 v0 = *(const us8*)(hb + (size_t)srcs[j] * H1v);
        us8 v1 = *(const us8*)(hb + (size_t)srcs[j + 1] * H1v);
        us8 v2 = *(const us8*)(hb + (size_t)srcs[j + 2] * H1v);
        us8 v3 = *(const us8*)(hb + (size_t)srcs[j + 3] * H1v);
#pragma unroll
        for (int q = 0; q < 8; ++q)
            a[q] += bf2f(v0[q]) + bf2f(v1[q]) + bf2f(v2[q]) + bf2f(v3[q]);
    }
    for (; j < end; ++j) {
        us8 v = *(const us8*)(hb + (size_t)srcs[j] * H1v);
#pragma unroll
        for (int q = 0; q < 8; ++q) a[q] += bf2f(v[q]);
    }
    const float di = dinv[d];
    const float4 b0 = *(const float4*)(bias + fo);
    const float4 b1 = *(const float4*)(bias + fo + 4);
    float4 o0, o1;
    o0.x = fmaxf(fmaf(di, a[0], b0.x), 0.f);
    o0.y = fmaxf(fmaf(di, a[1], b0.y), 0.f);
    o0.z = fmaxf(fmaf(di, a[2], b0.z), 0.f);
    o0.w = fmaxf(fmaf(di, a[3], b0.w), 0.f);
    o1.x = fmaxf(fmaf(di, a[4], b1.x), 0.f);
    o1.y = fmaxf(fmaf(di, a[5], b1.y), 0.f);
    o1.z = fmaxf(fmaf(di, a[6], b1.z), 0.f);
    o1.w = fmaxf(fmaf(di, a[7], b1.w), 0.f);
    *(float4*)(out + (size_t)d * H1v + fo) = o0;
    *(float4*)(out + (size_t)d * H1v + fo + 4) = o1;
}

// ---------------- fused: agg over h2 (D=32) + GEMM3 [32x16] -> h3 bf16 ----------

__global__ __launch_bounds__(256) void k_agg32_gemm3(const unsigned short* __restrict__ h2,
                                                     const int* __restrict__ rp,
                                                     const int* __restrict__ srcs,
                                                     const float* __restrict__ dinv,
                                                     const float* __restrict__ b2,
                                                     const float* __restrict__ W3,
                                                     unsigned short* __restrict__ h3) {
    __shared__ float als[16][33];      // +1 pad
    __shared__ float W3s[H2v * Cv];    // 512 floats
    const int t = threadIdx.x;
    *(float2*)(&W3s[t * 2]) = *(const float2*)(W3 + t * 2);

    const int sub = t >> 4, fg = t & 15;   // row slot, dim-pair group
    const int d = blockIdx.x * 16 + sub;   // N % 16 == 0
    const int beg = rp[d], end = rp[d + 1];
    const unsigned short* h2b = h2 + fg * 2;
    unsigned sv = *(const unsigned*)(h2b + (size_t)d * H2v);
    float a0 = __uint_as_float(sv << 16);              // dim fg*2
    float a1 = __uint_as_float(sv & 0xffff0000u);      // dim fg*2+1
    int j = beg;
    for (; j + 3 < end; j += 4) {
        unsigned v0 = *(const unsigned*)(h2b + (size_t)srcs[j] * H2v);
        unsigned v1 = *(const unsigned*)(h2b + (size_t)srcs[j + 1] * H2v);
        unsigned v2 = *(const unsigned*)(h2b + (size_t)srcs[j + 2] * H2v);
        unsigned v3 = *(const unsigned*)(h2b + (size_t)srcs[j + 3] * H2v);
        a0 += __uint_as_float(v0 << 16) + __uint_as_float(v1 << 16)
            + __uint_as_float(v2 << 16) + __uint_as_float(v3 << 16);
        a1 += __uint_as_float(v0 & 0xffff0000u) + __uint_as_float(v1 & 0xffff0000u)
            + __uint_as_float(v2 & 0xffff0000u) + __uint_as_float(v3 & 0xffff0000u);
    }
    for (; j < end; ++j) {
        unsigned v = *(const unsigned*)(h2b + (size_t)srcs[j] * H2v);
        a0 += __uint_as_float(v << 16);
        a1 += __uint_as_float(v & 0xffff0000u);
    }
    const float di = dinv[d];
    als[sub][fg * 2]     = fmaxf(fmaf(di, a0, b2[fg * 2]), 0.f);
    als[sub][fg * 2 + 1] = fmaxf(fmaf(di, a1, b2[fg * 2 + 1]), 0.f);
    __syncthreads();

    const int row = t >> 4, col = t & 15;
    float sum = 0.f;
#pragma unroll
    for (int k = 0; k < H2v; ++k) sum = fmaf(als[row][k], W3s[k * Cv + col], sum);
    const int gr = blockIdx.x * 16 + row;
    h3[(size_t)gr * Cv + col] = f2bf(sum * dinv[gr]);
}

// ---------------- final aggregation over h3 (D=16) -> out fp32 ----------------

__global__ __launch_bounds__(256) void k_agg16(const unsigned short* __restrict__ h,
                                               const int* __restrict__ rp,
                                               const int* __restrict__ srcs,
                                               const float* __restrict__ dinv,
                                               const float* __restrict__ bias,
                                               float* __restrict__ out) {
    const int sub = threadIdx.x >> 3;      // row slot 0..31
    const int fg = threadIdx.x & 7;        // dim-pair group
    const int d = blockIdx.x * 32 + sub;
    if (d >= N) return;
    const int beg = rp[d], end = rp[d + 1];
    const unsigned short* hb = h + fg * 2;
    unsigned sv = *(const unsigned*)(hb + (size_t)d * Cv);
    float a0 = __uint_as_float(sv << 16);
    float a1 = __uint_as_float(sv & 0xffff0000u);
    int j = beg;
    for (; j + 3 < end; j += 4) {
        unsigned v0 = *(const unsigned*)(hb + (size_t)srcs[j] * Cv);
        unsigned v1 = *(const unsigned*)(hb + (size_t)srcs[j + 1] * Cv);
        unsigned v2 = *(const unsigned*)(hb + (size_t)srcs[j + 2] * Cv);
        unsigned v3 = *(const unsigned*)(hb + (size_t)srcs[j + 3] * Cv);
        a0 += __uint_as_float(v0 << 16) + __uint_as_float(v1 << 16)
            + __uint_as_float(v2 << 16) + __uint_as_float(v3 << 16);
        a1 += __uint_as_float(v0 & 0xffff0000u) + __uint_as_float(v1 & 0xffff0000u)
            + __uint_as_float(v2 & 0xffff0000u) + __uint_as_float(v3 & 0xffff0000u);
    }
    for (; j < end; ++j) {
        unsigned v = *(const unsigned*)(hb + (size_t)srcs[j] * Cv);
        a0 += __uint_as_float(v << 16);
        a1 += __uint_as_float(v & 0xffff0000u);
    }
    const float di = dinv[d];
    float2 o;
    o.x = fmaf(di, a0, bias[fg * 2]);
    o.y = fmaf(di, a1, bias[fg * 2 + 1]);
    *(float2*)(out + (size_t)d * Cv + fg * 2) = o;
}

// ---------------- launch ----------------

extern "C" void kernel_launch(void* const* d_in, const int* in_sizes, int n_in,
                              void* d_out, int out_size, void* d_ws, size_t ws_size,
                              hipStream_t stream) {
    const float* x  = (const float*)d_in[0];
    const int*   ei = (const int*)d_in[1];
    const float* W1 = (const float*)d_in[2];
    const float* b1 = (const float*)d_in[3];
    const float* W2 = (const float*)d_in[4];
    const float* b2 = (const float*)d_in[5];
    const float* W3 = (const float*)d_in[6];
    const float* b3 = (const float*)d_in[7];
    const int* src = ei;       // edge_index[0]
    const int* dst = ei + E;   // edge_index[1]
    float* out = (float*)d_out;

    // Workspace layout (bytes):
    // [0       ] dinv    float[50000]
    // [0x40000 ] cnt/rp  int[50001]   (in-place scan)
    // [0x80000 ] cursor  int[50000]
    // [0xB2000 ] bsum    int[49]
    // [0xC0000 ] srcs    int[800000]
    // [4 MiB   ] Wsplit  ushort[262144]  (512 KB)
    // [5 MiB   ] h1 bf16, a1 fp32, h2 bf16, h3 bf16
    char* ws = (char*)d_ws;
    float* dinv   = (float*)ws;
    int*   cnt    = (int*)(ws + 0x40000);
    int*   rp     = cnt;
    int*   cursor = (int*)(ws + 0x80000);
    int*   bsum   = (int*)(ws + 0xB2000);
    int*   srcs   = (int*)(ws + 0xC0000);
    unsigned short* wsplit = (unsigned short*)(ws + (size_t)4 * 1024 * 1024);
    char* p = ws + (size_t)5 * 1024 * 1024;
    unsigned short* h1 = (unsigned short*)p; p += (size_t)N * H1v * sizeof(unsigned short);
    float*          a1 = (float*)p;          p += (size_t)N * H1v * sizeof(float);
    unsigned short* h2 = (unsigned short*)p; p += (size_t)N * H2v * sizeof(unsigned short);
    unsigned short* h3 = (unsigned short*)p;

    // CSR build + weight split: 5 dispatches
    k_init<<<64 + (N + 256) / 256, 256, 0, stream>>>(W1, wsplit, cnt);
    k_hist<<<(E + 255) / 256, 256, 0, stream>>>(dst, cnt);
    k_scan_part<<<NBLK, 256, 0, stream>>>(cnt, bsum);
    k_scan_final<<<NBLK, 256, 0, stream>>>(cnt, bsum, rp, cursor, dinv);
    k_permute<<<(E + 255) / 256, 256, 0, stream>>>(src, dst, cursor, srcs);

    // ---- layer 1: 512 -> 256 (MFMA), 4 row-chunk dispatches (diagnostic split) ----
    dim3 g1(196, 2);  // 196*64 = 12544 rows per chunk; 4*12544 >= N
    for (int c = 0; c < 4; ++c)
        k_gemm1_mfma<<<g1, 256, 0, stream>>>(x, wsplit, dinv, h1, c * 12544);
    k_agg_d256<<<(N + 7) / 8, 256, 0, stream>>>(h1, rp, srcs, dinv, b1, a1);

    // ---- layer 2: 256 -> 32, ReLU ----
    k_gemm2<<<(N + 31) / 32, 256, 0, stream>>>(a1, W2, dinv, h2);

    // ---- fused: agg(h2) + GEMM3 -> h3 ----
    k_agg32_gemm3<<<N / 16, 256, 0, stream>>>(h2, rp, srcs, dinv, b2, W3, h3);

    // ---- final aggregation -> out ----
    k_agg16<<<(N + 31) / 32, 256, 0, stream>>>(h3, rp, srcs, dinv, b3, out);
}

// Round 9
// 380.317 us; speedup vs baseline: 1.3388x; 1.3388x over previous
//
#include <hip/hip_runtime.h>

// Problem constants (from reference)
constexpr int N   = 50000;
constexpr int E   = 800000;
constexpr int FIN = 512;
constexpr int H1v = 256;
constexpr int H2v = 32;
constexpr int Cv  = 16;

constexpr int NBLK = (N + 1023) / 1024;  // 49 scan blocks

typedef __attribute__((ext_vector_type(8))) short short8;            // 8 bf16 (MFMA frag)
typedef __attribute__((ext_vector_type(4))) float f32x4;             // MFMA C/D frag
typedef __attribute__((ext_vector_type(4))) unsigned short us4;      // 4 bf16
typedef __attribute__((ext_vector_type(8))) unsigned short us8;      // 8 bf16 (16 B)
typedef __attribute__((ext_vector_type(4))) unsigned int uint4v;

// fp32 -> bf16 round-to-nearest-even, and back
__device__ inline unsigned short f2bf(float f) {
    unsigned u = __float_as_uint(f);
    return (unsigned short)((u + 0x7FFFu + ((u >> 16) & 1u)) >> 16);
}
__device__ inline float bf2f(unsigned short b) { return __uint_as_float(((unsigned)b) << 16); }

// ---------------- init: cnt zeroing + W1/W2 split, fused (independent data) -----
// Blocks 0..63:  W1 split into bf16 hi/lo MFMA B-frag layout (16 ktg x 16 ntg).
// Blocks 64..67: W2 split likewise (8 ktg x 2 ntg tiles).
// Blocks 68.. :  cnt[0..N] = 0.
// Frag layout per tile: B[k][n], k=ktg*32+(l>>4)*8+j, n=ntg*16+(l&15);
// tile base = tileIdx*1024; hi at +l*8, lo at +512+l*8.

__global__ __launch_bounds__(256) void k_init(const float* __restrict__ W1,
                                              const float* __restrict__ W2,
                                              unsigned short* __restrict__ Wf,
                                              unsigned short* __restrict__ Wf2,
                                              int* __restrict__ cnt) {
    const int b = blockIdx.x;
    if (b < 64) {
        int t = b * 256 + threadIdx.x;  // 0..16383
        int l = t & 63, nt = (t >> 6) & 15, kt = t >> 10;
        int n = nt * 16 + (l & 15);
        int kb = kt * 32 + (l >> 4) * 8;
        short8 h8, l8;
#pragma unroll
        for (int j = 0; j < 8; ++j) {
            float w = W1[(size_t)(kb + j) * H1v + n];
            unsigned short h = f2bf(w);
            h8[j] = (short)h;
            l8[j] = (short)f2bf(w - bf2f(h));
        }
        size_t base = (size_t)(kt * 16 + nt) * 1024 + (size_t)l * 8;
        *(short8*)(Wf + base) = h8;
        *(short8*)(Wf + base + 512) = l8;
    } else if (b < 68) {
        int t = (b - 64) * 256 + threadIdx.x;  // 0..1023
        int l = t & 63, nt = (t >> 6) & 1, kt = t >> 7;  // kt 0..7
        int n = nt * 16 + (l & 15);
        int kb = kt * 32 + (l >> 4) * 8;
        short8 h8, l8;
#pragma unroll
        for (int j = 0; j < 8; ++j) {
            float w = W2[(size_t)(kb + j) * H2v + n];
            unsigned short h = f2bf(w);
            h8[j] = (short)h;
            l8[j] = (short)f2bf(w - bf2f(h));
        }
        size_t base = (size_t)(kt * 2 + nt) * 1024 + (size_t)l * 8;
        *(short8*)(Wf2 + base) = h8;
        *(short8*)(Wf2 + base + 512) = l8;
    } else {
        int i = (b - 68) * 256 + threadIdx.x;
        if (i <= N) cnt[i] = 0;
    }
}

// ---------------- degree histogram / CSR build ----------------

__global__ __launch_bounds__(256) void k_hist(const int* __restrict__ dst,
                                              int* __restrict__ cnt) {
    int e = blockIdx.x * 256 + threadIdx.x;
    if (e < E) atomicAdd(&cnt[dst[e]], 1);
}

// Phase 1: per-block (1024 elems) sums.
__global__ __launch_bounds__(256) void k_scan_part(const int* __restrict__ cnt,
                                                   int* __restrict__ bsum) {
    __shared__ int red[256];
    const int t = threadIdx.x;
    const int base = blockIdx.x * 1024 + t * 4;
    int s = 0;
#pragma unroll
    for (int i = 0; i < 4; ++i) {
        int idx = base + i;
        if (idx < N) s += cnt[idx];
    }
    red[t] = s;
    __syncthreads();
    for (int off = 128; off > 0; off >>= 1) {
        if (t < off) red[t] += red[t + off];
        __syncthreads();
    }
    if (t == 0) bsum[blockIdx.x] = red[0];
}

// Phase 2 (fused top + final)
__global__ __launch_bounds__(256) void k_scan_final(const int* __restrict__ cnt,
                                                    const int* __restrict__ bsum,
                                                    int* __restrict__ row_ptr,
                                                    int* __restrict__ cursor,
                                                    float* __restrict__ dinv) {
    __shared__ int sums[256];
    __shared__ int s_bofs, s_tot;
    const int t = threadIdx.x;

    if (t < 64) {
        int v = (t < NBLK) ? bsum[t] : 0;
        int pre = (t < (int)blockIdx.x) ? v : 0;
#pragma unroll
        for (int off = 32; off > 0; off >>= 1) {
            pre += __shfl_down(pre, off, 64);
            v   += __shfl_down(v, off, 64);
        }
        if (t == 0) { s_bofs = pre; s_tot = v; }
    }

    const int base = blockIdx.x * 1024 + t * 4;
    int v[4];
    int local = 0;
#pragma unroll
    for (int i = 0; i < 4; ++i) {
        int idx = base + i;
        v[i] = (idx < N) ? cnt[idx] : 0;
        local += v[i];
    }
    sums[t] = local;
    __syncthreads();
    for (int off = 1; off < 256; off <<= 1) {
        int u = (t >= off) ? sums[t - off] : 0;
        __syncthreads();
        sums[t] += u;
        __syncthreads();
    }
    int run = s_bofs + sums[t] - local;  // exclusive thread offset
#pragma unroll
    for (int i = 0; i < 4; ++i) {
        int idx = base + i;
        if (idx < N) {
            row_ptr[idx] = run;
            cursor[idx] = run;
            dinv[idx] = rsqrtf(1.0f + (float)v[i]);  // +1 self-loop
        }
        run += v[i];
    }
    if (blockIdx.x == NBLK - 1 && t == 0) row_ptr[N] = s_tot;  // == E
}

__global__ __launch_bounds__(256) void k_permute(const int* __restrict__ src,
                                                 const int* __restrict__ dst,
                                                 int* __restrict__ cursor,
                                                 int* __restrict__ srcs) {
    int e = blockIdx.x * 256 + threadIdx.x;
    if (e < E) {
        int pos = atomicAdd(&cursor[dst[e]], 1);
        srcs[pos] = src[e];
    }
}

// ---------------- GEMM 1 (MFMA, split-bf16 x3): [N,512]@[512,256] ---------------
// ROUND 17: SINGLE dispatch again (782,2). R16's 4-way split put 392 blocks/
// dispatch = 1.5 blk/CU, violating the R10 occupancy lesson -> regressed. The
// diagnostic did its job (exposed gemm2 at 107us, MfmaUtil 0, broadcast loads).
// Structure stays R14-best (BK=64, conflict-free, ~77us).

__device__ inline void split_pair(float x0, float x1, unsigned& hp, unsigned& lp) {
    unsigned u0 = __float_as_uint(x0), u1 = __float_as_uint(x1);
    unsigned h0 = u0 & 0xffff0000u, h1 = u1 & 0xffff0000u;
    float l0 = x0 - __uint_as_float(h0);
    float l1 = x1 - __uint_as_float(h1);
    hp = __builtin_amdgcn_perm(u1, u0, 0x07060302u);  // [u0.hi16, u1.hi16]
    lp = __builtin_amdgcn_perm(__float_as_uint(l1), __float_as_uint(l0), 0x07060302u);
}

__device__ inline void split_frag(const float4& a, const float4& b, short8& hi, short8& lo) {
    unsigned h0, h1, h2, h3, l0, l1, l2, l3;
    split_pair(a.x, a.y, h0, l0);
    split_pair(a.z, a.w, h1, l1);
    split_pair(b.x, b.y, h2, l2);
    split_pair(b.z, b.w, h3, l3);
    uint4v h, l;
    h[0] = h0; h[1] = h1; h[2] = h2; h[3] = h3;
    l[0] = l0; l[1] = l1; l[2] = l2; l[3] = l3;
    hi = __builtin_bit_cast(short8, h);
    lo = __builtin_bit_cast(short8, l);
}

// Stage one 64-row x 64-col fp32 X tile into LDS (16 KB), XOR-swizzled.
__device__ inline void stage_x_tile(const float* __restrict__ X, int brow, int k0,
                                    float* lds, int tid) {
    const int wbase = tid & ~63;  // wave-uniform chunk base
#pragma unroll
    for (int c = 0; c < 4; ++c) {
        int q = c * 256 + tid;
        int row = q >> 4;
        int gc = ((q & 15) ^ (row & 15)) << 2;  // swizzled source col (floats)
        int r = brow + row;
        const float* src = X + (size_t)(r < N ? r : 0) * FIN + k0 + gc;
        float* dst = lds + (size_t)(c * 256 + wbase) * 4;  // wave-uniform, lane adds 16B
        __builtin_amdgcn_global_load_lds((const __attribute__((address_space(1))) void*)src,
                                         (__attribute__((address_space(3))) void*)dst,
                                         16, 0, 0);
    }
}

__global__ __launch_bounds__(256, 4) void k_gemm1_mfma(const float* __restrict__ X,
                                                       const unsigned short* __restrict__ Wf,
                                                       const float* __restrict__ dinv,
                                                       unsigned short* __restrict__ Hout) {
    __shared__ float As[2][4096];  // 2 x (64 rows x 64 cols) fp32 = 32 KB
    const int tid = threadIdx.x;
    const int w = tid >> 6, l = tid & 63;
    const int wr = w >> 1, wc = w & 1;        // wave: 32-row group x 64-col group
    const int brow = blockIdx.x * 64;         // block row base
    const int row0 = brow + wr * 32;          // this wave's global row base
    const int wrow = wr * 32;                 // this wave's LDS-local row base
    const int colb = blockIdx.y;
    const int lm = l & 15;
    const int lk2 = (l >> 4) * 2;             // fragment granule pair base (16B units)

    // B frag lane pointer (tiles ntg = colb*8 + wc*4 + j)
    const unsigned short* bp0 = Wf + (size_t)(colb * 8 + wc * 4) * 1024 + (size_t)l * 8;

    f32x4 acc[2][4];
#pragma unroll
    for (int i = 0; i < 2; ++i)
#pragma unroll
        for (int j = 0; j < 4; ++j) acc[i][j] = (f32x4)0.f;

    // prologue: stage K-tile 0 (64 cols)
    stage_x_tile(X, brow, 0, As[0], tid);

    for (int kt = 0; kt < 8; ++kt) {
        const int cur = kt & 1;
        __syncthreads();  // drains vmcnt(0): As[cur] staged & visible

        // B frags for sub-step 0 (ktg = 2*kt), L2-hot frag layout
        const unsigned short* bpA = bp0 + (size_t)(2 * kt) * 16384;
        short8 B0h[4], B0l[4];
#pragma unroll
        for (int j = 0; j < 4; ++j) {
            B0h[j] = *(const short8*)(bpA + j * 1024);
            B0l[j] = *(const short8*)(bpA + j * 1024 + 512);
        }

        // stage next 64-col K-tile (completes during the two MFMA phases)
        if (kt < 7) stage_x_tile(X, brow, (kt + 1) * 64, As[cur ^ 1], tid);

        const float* Ab = As[cur];

        // ---- sub-step 0: granules [0,8) ----
        short8 Ah[2], Al[2];
#pragma unroll
        for (int i = 0; i < 2; ++i) {
            int row = wrow + i * 16 + lm;
            const float* rbp = Ab + row * 64;
            int p = row & 15;
            float4 a0 = *(const float4*)(rbp + ((lk2 ^ p) << 2));
            float4 a1 = *(const float4*)(rbp + (((lk2 + 1) ^ p) << 2));
            split_frag(a0, a1, Ah[i], Al[i]);
        }

        // B frags for sub-step 1 issued BEFORE MFMA block 0 (latency covered by it)
        const unsigned short* bpB = bpA + 16384;
        short8 B1h[4], B1l[4];
#pragma unroll
        for (int j = 0; j < 4; ++j) {
            B1h[j] = *(const short8*)(bpB + j * 1024);
            B1l[j] = *(const short8*)(bpB + j * 1024 + 512);
        }

#pragma unroll
        for (int i = 0; i < 2; ++i)
#pragma unroll
            for (int j = 0; j < 4; ++j) {
                acc[i][j] = __builtin_amdgcn_mfma_f32_16x16x32_bf16(Ah[i], B0h[j], acc[i][j], 0, 0, 0);
                acc[i][j] = __builtin_amdgcn_mfma_f32_16x16x32_bf16(Ah[i], B0l[j], acc[i][j], 0, 0, 0);
                acc[i][j] = __builtin_amdgcn_mfma_f32_16x16x32_bf16(Al[i], B0h[j], acc[i][j], 0, 0, 0);
            }

        // ---- sub-step 1: granules [8,16) ----
#pragma unroll
        for (int i = 0; i < 2; ++i) {
            int row = wrow + i * 16 + lm;
            const float* rbp = Ab + row * 64;
            int p = row & 15;
            int g0 = lk2 + 8;
            float4 a0 = *(const float4*)(rbp + ((g0 ^ p) << 2));
            float4 a1 = *(const float4*)(rbp + (((g0 + 1) ^ p) << 2));
            split_frag(a0, a1, Ah[i], Al[i]);
        }

#pragma unroll
        for (int i = 0; i < 2; ++i)
#pragma unroll
            for (int j = 0; j < 4; ++j) {
                acc[i][j] = __builtin_amdgcn_mfma_f32_16x16x32_bf16(Ah[i], B1h[j], acc[i][j], 0, 0, 0);
                acc[i][j] = __builtin_amdgcn_mfma_f32_16x16x32_bf16(Ah[i], B1l[j], acc[i][j], 0, 0, 0);
                acc[i][j] = __builtin_amdgcn_mfma_f32_16x16x32_bf16(Al[i], B1h[j], acc[i][j], 0, 0, 0);
            }
    }

    // ---- epilogue: C row = (l>>4)*4 + reg, col = l&15 ; *dinv[row], store bf16 ----
    const int col0 = colb * 128 + wc * 64;
#pragma unroll
    for (int i = 0; i < 2; ++i) {
        int rbase = row0 + i * 16 + (l >> 4) * 4;
        float dv[4];
        bool okr[4];
#pragma unroll
        for (int r = 0; r < 4; ++r) {
            int rr = rbase + r;
            okr[r] = rr < N;
            dv[r] = okr[r] ? dinv[rr] : 0.f;
        }
#pragma unroll
        for (int j = 0; j < 4; ++j) {
            int col = col0 + j * 16 + lm;
#pragma unroll
            for (int r = 0; r < 4; ++r)
                if (okr[r]) Hout[(size_t)(rbase + r) * H1v + col] = f2bf(acc[i][j][r] * dv[r]);
        }
    }
}

// ---------------- GEMM 2 (MFMA, split-bf16 x3): [N,256]@[256,32] ----------------
// ROUND 17: replaces the broadcast-load k_gemm2 (107us, MfmaUtil 0, 2 distinct
// addrs/wave-step). A staged coalesced via global_load_lds (16B/lane), W2
// pre-split by k_init. 64 rows x 32 cols per block, K-loop 8, dbuf 16KB LDS.
// Same split-bf16 x3 precision structure as gemm1.

// Stage one 64-row x 32-col fp32 tile of A (row stride H1v) into LDS, swizzled.
__device__ inline void stage_a_tile(const float* __restrict__ A, int brow, int k0,
                                    float* lds, int tid) {
    const int wbase = tid & ~63;
#pragma unroll
    for (int c = 0; c < 2; ++c) {
        int q = c * 256 + tid;           // 0..511
        int row = q >> 3;
        int gc = ((q & 7) ^ (row & 7)) << 2;  // swizzled source col (floats)
        int r = brow + row;
        const float* src = A + (size_t)(r < N ? r : 0) * H1v + k0 + gc;
        float* dst = lds + (size_t)(c * 256 + wbase) * 4;
        __builtin_amdgcn_global_load_lds((const __attribute__((address_space(1))) void*)src,
                                         (__attribute__((address_space(3))) void*)dst,
                                         16, 0, 0);
    }
}

__global__ __launch_bounds__(256, 4) void k_gemm2_mfma(const float* __restrict__ A,
                                                       const unsigned short* __restrict__ Wf2,
                                                       const float* __restrict__ dinv,
                                                       unsigned short* __restrict__ Hout) {
    __shared__ float As[2][2048];  // 2 x (64 rows x 32 cols) fp32 = 16 KB
    const int tid = threadIdx.x;
    const int w = tid >> 6, l = tid & 63;
    const int brow = blockIdx.x * 64;
    const int wrow = w * 16;                  // wave's 16-row slice
    const int lm = l & 15;
    const int lk2 = (l >> 4) * 2;

    const unsigned short* bp0 = Wf2 + (size_t)l * 8;

    f32x4 acc[2];
    acc[0] = (f32x4)0.f;
    acc[1] = (f32x4)0.f;

    stage_a_tile(A, brow, 0, As[0], tid);

    for (int kt = 0; kt < 8; ++kt) {
        const int cur = kt & 1;
        __syncthreads();

        // B frags (2 ntg tiles), L2-hot
        const unsigned short* bp = bp0 + (size_t)kt * 2048;
        short8 Bh[2], Bl[2];
#pragma unroll
        for (int j = 0; j < 2; ++j) {
            Bh[j] = *(const short8*)(bp + j * 1024);
            Bl[j] = *(const short8*)(bp + j * 1024 + 512);
        }

        if (kt < 7) stage_a_tile(A, brow, (kt + 1) * 32, As[cur ^ 1], tid);

        // A frag from LDS (swizzled), split
        int row = wrow + lm;
        const float* rbp = As[cur] + row * 32;
        int p = row & 7;
        float4 a0 = *(const float4*)(rbp + ((lk2 ^ p) << 2));
        float4 a1 = *(const float4*)(rbp + (((lk2 + 1) ^ p) << 2));
        short8 Ah, Al;
        split_frag(a0, a1, Ah, Al);

#pragma unroll
        for (int j = 0; j < 2; ++j) {
            acc[j] = __builtin_amdgcn_mfma_f32_16x16x32_bf16(Ah, Bh[j], acc[j], 0, 0, 0);
            acc[j] = __builtin_amdgcn_mfma_f32_16x16x32_bf16(Ah, Bl[j], acc[j], 0, 0, 0);
            acc[j] = __builtin_amdgcn_mfma_f32_16x16x32_bf16(Al, Bh[j], acc[j], 0, 0, 0);
        }
    }

    // epilogue: row = brow + wrow + (l>>4)*4 + r, col = j*16 + lm
    const int rbase = brow + wrow + (l >> 4) * 4;
    float dv[4];
    bool okr[4];
#pragma unroll
    for (int r = 0; r < 4; ++r) {
        int rr = rbase + r;
        okr[r] = rr < N;
        dv[r] = okr[r] ? dinv[rr] : 0.f;
    }
#pragma unroll
    for (int j = 0; j < 2; ++j) {
        int col = j * 16 + lm;
#pragma unroll
        for (int r = 0; r < 4; ++r)
            if (okr[r]) Hout[(size_t)(rbase + r) * H2v + col] = f2bf(acc[j][r] * dv[r]);
    }
}

// ---------------- CSR aggregation D=256 (atomic-free, bf16 msgs, fp32 accum) -----

__global__ __launch_bounds__(256) void k_agg_d256(const unsigned short* __restrict__ h,
                                                  const int* __restrict__ rp,
                                                  const int* __restrict__ srcs,
                                                  const float* __restrict__ dinv,
                                                  const float* __restrict__ bias,
                                                  float* __restrict__ out) {
    const int half = threadIdx.x >> 5;     // row slot 0..7 in block
    const int lane = threadIdx.x & 31;
    const int d = blockIdx.x * 8 + half;
    if (d >= N) return;
    const int beg = rp[d], end = rp[d + 1];
    const int fo = lane * 8;               // 8 bf16 = 16 B per lane
    const unsigned short* hb = h + fo;
    us8 sv = *(const us8*)(hb + (size_t)d * H1v);  // self-loop
    float a[8];
#pragma unroll
    for (int q = 0; q < 8; ++q) a[q] = bf2f(sv[q]);
    int j = beg;
    for (; j + 7 < end; j += 8) {  // 8 independent 16B gathers per row
        us8 v0 = *(const us8*)(hb + (size_t)srcs[j] * H1v);
        us8 v1 = *(const us8*)(hb + (size_t)srcs[j + 1] * H1v);
        us8 v2 = *(const us8*)(hb + (size_t)srcs[j + 2] * H1v);
        us8 v3 = *(const us8*)(hb + (size_t)srcs[j + 3] * H1v);
        us8 v4 = *(const us8*)(hb + (size_t)srcs[j + 4] * H1v);
        us8 v5 = *(const us8*)(hb + (size_t)srcs[j + 5] * H1v);
        us8 v6 = *(const us8*)(hb + (size_t)srcs[j + 6] * H1v);
        us8 v7 = *(const us8*)(hb + (size_t)srcs[j + 7] * H1v);
#pragma unroll
        for (int q = 0; q < 8; ++q)
            a[q] += ((bf2f(v0[q]) + bf2f(v1[q])) + (bf2f(v2[q]) + bf2f(v3[q])))
                  + ((bf2f(v4[q]) + bf2f(v5[q])) + (bf2f(v6[q]) + bf2f(v7[q])));
    }
    for (; j + 3 < end; j += 4) {
        us8 v0 = *(const us8*)(hb + (size_t)srcs[j] * H1v);
        us8 v1 = *(const us8*)(hb + (size_t)srcs[j + 1] * H1v);
        us8 v2 = *(const us8*)(hb + (size_t)srcs[j + 2] * H1v);
        us8 v3 = *(const us8*)(hb + (size_t)srcs[j + 3] * H1v);
#pragma unroll
        for (int q = 0; q < 8; ++q)
            a[q] += bf2f(v0[q]) + bf2f(v1[q]) + bf2f(v2[q]) + bf2f(v3[q]);
    }
    for (; j < end; ++j) {
        us8 v = *(const us8*)(hb + (size_t)srcs[j] * H1v);
#pragma unroll
        for (int q = 0; q < 8; ++q) a[q] += bf2f(v[q]);
    }
    const float di = dinv[d];
    const float4 b0 = *(const float4*)(bias + fo);
    const float4 b1 = *(const float4*)(bias + fo + 4);
    float4 o0, o1;
    o0.x = fmaxf(fmaf(di, a[0], b0.x), 0.f);
    o0.y = fmaxf(fmaf(di, a[1], b0.y), 0.f);
    o0.z = fmaxf(fmaf(di, a[2], b0.z), 0.f);
    o0.w = fmaxf(fmaf(di, a[3], b0.w), 0.f);
    o1.x = fmaxf(fmaf(di, a[4], b1.x), 0.f);
    o1.y = fmaxf(fmaf(di, a[5], b1.y), 0.f);
    o1.z = fmaxf(fmaf(di, a[6], b1.z), 0.f);
    o1.w = fmaxf(fmaf(di, a[7], b1.w), 0.f);
    *(float4*)(out + (size_t)d * H1v + fo) = o0;
    *(float4*)(out + (size_t)d * H1v + fo + 4) = o1;
}

// ---------------- fused: agg over h2 (D=32) + GEMM3 [32x16] -> h3 bf16 ----------

__global__ __launch_bounds__(256) void k_agg32_gemm3(const unsigned short* __restrict__ h2,
                                                     const int* __restrict__ rp,
                                                     const int* __restrict__ srcs,
                                                     const float* __restrict__ dinv,
                                                     const float* __restrict__ b2,
                                                     const float* __restrict__ W3,
                                                     unsigned short* __restrict__ h3) {
    __shared__ float als[16][33];      // +1 pad
    __shared__ float W3s[H2v * Cv];    // 512 floats
    const int t = threadIdx.x;
    *(float2*)(&W3s[t * 2]) = *(const float2*)(W3 + t * 2);

    const int sub = t >> 4, fg = t & 15;   // row slot, dim-pair group
    const int d = blockIdx.x * 16 + sub;   // N % 16 == 0
    const int beg = rp[d], end = rp[d + 1];
    const unsigned short* h2b = h2 + fg * 2;
    unsigned sv = *(const unsigned*)(h2b + (size_t)d * H2v);
    float a0 = __uint_as_float(sv << 16);              // dim fg*2
    float a1 = __uint_as_float(sv & 0xffff0000u);      // dim fg*2+1
    int j = beg;
    for (; j + 3 < end; j += 4) {
        unsigned v0 = *(const unsigned*)(h2b + (size_t)srcs[j] * H2v);
        unsigned v1 = *(const unsigned*)(h2b + (size_t)srcs[j + 1] * H2v);
        unsigned v2 = *(const unsigned*)(h2b + (size_t)srcs[j + 2] * H2v);
        unsigned v3 = *(const unsigned*)(h2b + (size_t)srcs[j + 3] * H2v);
        a0 += __uint_as_float(v0 << 16) + __uint_as_float(v1 << 16)
            + __uint_as_float(v2 << 16) + __uint_as_float(v3 << 16);
        a1 += __uint_as_float(v0 & 0xffff0000u) + __uint_as_float(v1 & 0xffff0000u)
            + __uint_as_float(v2 & 0xffff0000u) + __uint_as_float(v3 & 0xffff0000u);
    }
    for (; j < end; ++j) {
        unsigned v = *(const unsigned*)(h2b + (size_t)srcs[j] * H2v);
        a0 += __uint_as_float(v << 16);
        a1 += __uint_as_float(v & 0xffff0000u);
    }
    const float di = dinv[d];
    als[sub][fg * 2]     = fmaxf(fmaf(di, a0, b2[fg * 2]), 0.f);
    als[sub][fg * 2 + 1] = fmaxf(fmaf(di, a1, b2[fg * 2 + 1]), 0.f);
    __syncthreads();

    const int row = t >> 4, col = t & 15;
    float sum = 0.f;
#pragma unroll
    for (int k = 0; k < H2v; ++k) sum = fmaf(als[row][k], W3s[k * Cv + col], sum);
    const int gr = blockIdx.x * 16 + row;
    h3[(size_t)gr * Cv + col] = f2bf(sum * dinv[gr]);
}

// ---------------- final aggregation over h3 (D=16) -> out fp32 ----------------

__global__ __launch_bounds__(256) void k_agg16(const unsigned short* __restrict__ h,
                                               const int* __restrict__ rp,
                                               const int* __restrict__ srcs,
                                               const float* __restrict__ dinv,
                                               const float* __restrict__ bias,
                                               float* __restrict__ out) {
    const int sub = threadIdx.x >> 3;      // row slot 0..31
    const int fg = threadIdx.x & 7;        // dim-pair group
    const int d = blockIdx.x * 32 + sub;
    if (d >= N) return;
    const int beg = rp[d], end = rp[d + 1];
    const unsigned short* hb = h + fg * 2;
    unsigned sv = *(const unsigned*)(hb + (size_t)d * Cv);
    float a0 = __uint_as_float(sv << 16);
    float a1 = __uint_as_float(sv & 0xffff0000u);
    int j = beg;
    for (; j + 3 < end; j += 4) {
        unsigned v0 = *(const unsigned*)(hb + (size_t)srcs[j] * Cv);
        unsigned v1 = *(const unsigned*)(hb + (size_t)srcs[j + 1] * Cv);
        unsigned v2 = *(const unsigned*)(hb + (size_t)srcs[j + 2] * Cv);
        unsigned v3 = *(const unsigned*)(hb + (size_t)srcs[j + 3] * Cv);
        a0 += __uint_as_float(v0 << 16) + __uint_as_float(v1 << 16)
            + __uint_as_float(v2 << 16) + __uint_as_float(v3 << 16);
        a1 += __uint_as_float(v0 & 0xffff0000u) + __uint_as_float(v1 & 0xffff0000u)
            + __uint_as_float(v2 & 0xffff0000u) + __uint_as_float(v3 & 0xffff0000u);
    }
    for (; j < end; ++j) {
        unsigned v = *(const unsigned*)(hb + (size_t)srcs[j] * Cv);
        a0 += __uint_as_float(v << 16);
        a1 += __uint_as_float(v & 0xffff0000u);
    }
    const float di = dinv[d];
    float2 o;
    o.x = fmaf(di, a0, bias[fg * 2]);
    o.y = fmaf(di, a1, bias[fg * 2 + 1]);
    *(float2*)(out + (size_t)d * Cv + fg * 2) = o;
}

// ---------------- launch ----------------

extern "C" void kernel_launch(void* const* d_in, const int* in_sizes, int n_in,
                              void* d_out, int out_size, void* d_ws, size_t ws_size,
                              hipStream_t stream) {
    const float* x  = (const float*)d_in[0];
    const int*   ei = (const int*)d_in[1];
    const float* W1 = (const float*)d_in[2];
    const float* b1 = (const float*)d_in[3];
    const float* W2 = (const float*)d_in[4];
    const float* b2 = (const float*)d_in[5];
    const float* W3 = (const float*)d_in[6];
    const float* b3 = (const float*)d_in[7];
    const int* src = ei;       // edge_index[0]
    const int* dst = ei + E;   // edge_index[1]
    float* out = (float*)d_out;

    // Workspace layout (bytes):
    // [0       ] dinv    float[50000]
    // [0x40000 ] cnt/rp  int[50001]   (in-place scan)
    // [0x80000 ] cursor  int[50000]
    // [0xB2000 ] bsum    int[49]
    // [0xC0000 ] srcs    int[800000]
    // [4 MiB   ] Wsplit  ushort[262144]  (512 KB)
    // [4.5 MiB ] Wsplit2 ushort[16384]   (32 KB)
    // [5 MiB   ] h1 bf16, a1 fp32, h2 bf16, h3 bf16
    char* ws = (char*)d_ws;
    float* dinv   = (float*)ws;
    int*   cnt    = (int*)(ws + 0x40000);
    int*   rp     = cnt;
    int*   cursor = (int*)(ws + 0x80000);
    int*   bsum   = (int*)(ws + 0xB2000);
    int*   srcs   = (int*)(ws + 0xC0000);
    unsigned short* wsplit  = (unsigned short*)(ws + (size_t)4 * 1024 * 1024);
    unsigned short* wsplit2 = (unsigned short*)(ws + (size_t)4 * 1024 * 1024 + 512 * 1024);
    char* p = ws + (size_t)5 * 1024 * 1024;
    unsigned short* h1 = (unsigned short*)p; p += (size_t)N * H1v * sizeof(unsigned short);
    float*          a1 = (float*)p;          p += (size_t)N * H1v * sizeof(float);
    unsigned short* h2 = (unsigned short*)p; p += (size_t)N * H2v * sizeof(unsigned short);
    unsigned short* h3 = (unsigned short*)p;

    // CSR build + weight split: 5 dispatches
    k_init<<<68 + (N + 256) / 256, 256, 0, stream>>>(W1, W2, wsplit, wsplit2, cnt);
    k_hist<<<(E + 255) / 256, 256, 0, stream>>>(dst, cnt);
    k_scan_part<<<NBLK, 256, 0, stream>>>(cnt, bsum);
    k_scan_final<<<NBLK, 256, 0, stream>>>(cnt, bsum, rp, cursor, dinv);
    k_permute<<<(E + 255) / 256, 256, 0, stream>>>(src, dst, cursor, srcs);

    // ---- layer 1: 512 -> 256 (MFMA, single dispatch), ReLU ----
    dim3 g1((N + 63) / 64, 2);
    k_gemm1_mfma<<<g1, 256, 0, stream>>>(x, wsplit, dinv, h1);
    k_agg_d256<<<(N + 7) / 8, 256, 0, stream>>>(h1, rp, srcs, dinv, b1, a1);

    // ---- layer 2: 256 -> 32 (MFMA), ReLU fused downstream ----
    k_gemm2_mfma<<<(N + 63) / 64, 256, 0, stream>>>(a1, wsplit2, dinv, h2);

    // ---- fused: agg(h2) + GEMM3 -> h3 ----
    k_agg32_gemm3<<<N / 16, 256, 0, stream>>>(h2, rp, srcs, dinv, b2, W3, h3);

    // ---- final aggregation -> out ----
    k_agg16<<<(N + 31) / 32, 256, 0, stream>>>(h3, rp, srcs, dinv, b3, out);
}